// Round 17
// baseline (57.755 us; speedup 1.0000x reference)
//
#include <hip/hip_runtime.h>
#include <math.h>

#define BATCH 8
#define TDIM 2048
#define DDIM 512
#define SLOTB 2048       // bytes per packed row slot: [256B fp4 xq | pad | 1024B gelu bf16 @512]
#define NT 16            // number of 128-row tiles per batch
#define NTRI (NT*(NT+1)/2)
#define NUNITS (NTRI*BATCH)   // 1088
#define SIMBLK 256            // persistent simmax blocks (1/CU, 130KB LDS); 256%8==0 keeps XCD pinning
#define SCALE_E8M0 122   // 2^-5 per operand: compensates the x32 pre-scale (2^-10 total)

typedef unsigned short u16;
typedef float f32x4 __attribute__((ext_vector_type(4)));
typedef u16 u16x8 __attribute__((ext_vector_type(8)));
typedef int i32x4 __attribute__((ext_vector_type(4)));
typedef int i32x8 __attribute__((ext_vector_type(8)));

// fast tanh via single v_exp_f32: tanh(u) = 1 - 2/(exp(2u)+1)
__device__ __forceinline__ float tanh_fast(float u) {
    float e = __expf(2.0f * u);
    return 1.0f - 2.0f / (e + 1.0f);
}

__device__ __forceinline__ float gelu_f(float x) {
    const float c = 0.7978845608028654f; // sqrt(2/pi)
    return 0.5f * x * (1.0f + tanh_fast(c * (x + 0.044715f * x * x * x)));
}

__device__ __forceinline__ u16 f2bf(float f) {
    unsigned u = __float_as_uint(f);
    return (u16)((u + 0x7FFFu + ((u >> 16) & 1u)) >> 16); // RNE, no NaN inputs
}
__device__ __forceinline__ float bf2f(u16 h) {
    return __uint_as_float(((unsigned)h) << 16);
}

__device__ __forceinline__ float wave_sum(float v) {
    #pragma unroll
    for (int s = 1; s < 64; s <<= 1) v += __shfl_xor(v, s, 64);
    return v;
}

__device__ __forceinline__ void load_lds16(const void* g, void* l) {
    __builtin_amdgcn_global_load_lds(
        (const __attribute__((address_space(1))) void*)g,
        (__attribute__((address_space(3))) void*)l, 16, 0, 0);
}

// ---------------- kernel 1: norms, cos_ema, fp4 xq (x_n*32) + bf16 gelu ----------------
// XCD-aligned mapping: batch = blockIdx % 8 (same pinning as simmax).
// fp4 e2m1 magnitudes {0,.5,1,1.5,2,3,4,6}: code = #thresholds passed (RNE bins),
// sign in bit 3. Any consistent K-permutation of BOTH operands leaves the dot
// product invariant.
__global__ __launch_bounds__(256) void prep_kernel(
    const float* __restrict__ x, const float* __restrict__ ema,
    char* __restrict__ slots, float* __restrict__ cosema)
{
    const int wave = threadIdx.x >> 6;
    const int lane = threadIdx.x & 63;
    const int xb   = blockIdx.x & 7;          // batch == XCD
    const int ib   = blockIdx.x >> 3;         // 0..511 within batch
    const int row  = (xb << 11) + ib * 4 + wave; // 0 .. B*T-1

    const float* xr = x + (size_t)row * DDIM + lane * 8;
    float4 v0 = *reinterpret_cast<const float4*>(xr);
    float4 v1 = *reinterpret_cast<const float4*>(xr + 4);
    const float* er = ema + lane * 8;
    float4 e0 = *reinterpret_cast<const float4*>(er);
    float4 e1 = *reinterpret_cast<const float4*>(er + 4);

    float vx[8] = {v0.x,v0.y,v0.z,v0.w,v1.x,v1.y,v1.z,v1.w};
    float ve[8] = {e0.x,e0.y,e0.z,e0.w,e1.x,e1.y,e1.z,e1.w};
    float gg[8];

    float ssx=0.f, ssg=0.f, dge=0.f, sse=0.f;
    #pragma unroll
    for (int j=0;j<8;++j) {
        float xv = vx[j];
        ssx += xv*xv;
        float gv = gelu_f(xv);
        gg[j] = gv;
        ssg += gv*gv;
        dge += gv*ve[j];
        sse += ve[j]*ve[j];
    }
    ssx = wave_sum(ssx); ssg = wave_sum(ssg);
    dge = wave_sum(dge); sse = wave_sum(sse);

    // quantize x_n * 32 to fp4 e2m1 (MFMA scales 2^-5 x 2^-5 restore the product)
    float invx32 = 32.0f / fmaxf(sqrtf(ssx), 1e-12f);
    unsigned pack = 0;
    #pragma unroll
    for (int j=0;j<8;++j) {
        float z = vx[j] * invx32;
        float a = fabsf(z);
        int c = (a>=0.25f) + (a>=0.75f) + (a>=1.25f) + (a>=1.75f)
              + (a>=2.5f)  + (a>=3.5f)  + (a>=5.0f);
        c |= (z < 0.0f) ? 8 : 0;
        pack |= (unsigned)c << (4*j);
    }
    char* rowb = slots + (size_t)row * SLOTB;
    reinterpret_cast<unsigned*>(rowb)[lane] = pack;   // fp4 bytes [0,256)

    u16x8 hg;
    #pragma unroll
    for (int j=0;j<8;++j) hg[j] = f2bf(gg[j]);
    *reinterpret_cast<u16x8*>(rowb + 512 + lane * 16) = hg;  // gelu bytes [512,1536)

    if (lane == 0) {
        float c = dge / (fmaxf(sqrtf(ssg), 1e-12f) * fmaxf(sqrtf(sse), 1e-12f));
        c = fminf(fmaxf(c, -1.0f), 1.0f);
        cosema[row] = c;
    }
}

// -------- kernel 2: Xn*Xn^T row-max, MX-fp4 — persistent blocks, CROSS-UNIT prefetch --------
// The one untested mechanism: in all prior variants, stage(i)'s loads were
// drained by a vmcnt(0) placed between issue and compute (so full L2 latency
// was exposed every unit/K-step). Here stage(u+1) is issued at unit u's START,
// and unit u's compute (~3000 cyc) covers its latency:
//   iter: [issue stage(u+1) -> buf^1] [vmcnt(16): only u's loads] [s_barrier]
//         [compute u from buf] [reduce] [lgkmcnt(0) + s_barrier -- NO vmcnt!]
//         [part-write]
// global_load_lds is fire-and-forget DMA -> progresses during compute even at
// 1 block/CU. Hazards: stage(u+1) targets buf^1, last read in unit u-1 and
// fenced by u-1's post-reduce barrier; buf[cur] gated by each wave's own
// vmcnt(16) before the stage-ready barrier; prow/pcol write->read split by
// lgkmcnt(0)+barrier; rule-18 sched_barrier(0) after every wait/barrier.
// Diag units stage B redundantly (Bg==Ag) so in-flight count is uniformly 16.
__global__ __launch_bounds__(256) void simmax_kernel(
    const char* __restrict__ slots, float* __restrict__ part)
{
    __shared__ unsigned char sA[2][32768];   // [buf][G(16)][row(128)][16B]
    __shared__ unsigned char sB[2][32768];
    __shared__ float prow[2][128];
    __shared__ float pcol[2][128];

    const int tid  = threadIdx.x;
    const int lane = tid & 63;
    const int w    = tid >> 6;
    const int wm   = w >> 1, wn = w & 1;
    const int roff  = lane & 15;
    const int klane = lane >> 4;
    const i32x4 z4 = {0,0,0,0};

    auto decode = [](int u, int& b, int& rt, int& ct) {
        b = u & 7;
        int rem = u >> 3; rt = 0;
        while (rem >= (NT - rt)) { rem -= (NT - rt); ++rt; }
        ct = rt + rem;
    };

    auto stage = [&](int buf, int u) {
        int b, rt, ct; decode(u, b, rt, ct);
        const char* Ag = slots + ((size_t)b * TDIM + (size_t)rt * 128) * SLOTB;
        const char* Bg = slots + ((size_t)b * TDIM + (size_t)ct * 128) * SLOTB;
        #pragma unroll
        for (int i = 0; i < 8; ++i) {
            const int s = i*256 + tid;                   // 0..2047
            const int G = s >> 7, r = s & 127;           // granule, row
            const size_t srcoff = (size_t)r * SLOTB + G*16;
            load_lds16(Ag + srcoff, &sA[buf][i*4096 + w*1024]);
            load_lds16(Bg + srcoff, &sB[buf][i*4096 + w*1024]);  // diag: redundant copy
        }
    };

    int ucur = blockIdx.x;               // SIMBLK < NUNITS: always valid
    stage(0, ucur);

    for (int it = 0; ucur < NUNITS; ucur += SIMBLK, ++it) {
        const int cur = it & 1;
        const int unext = ucur + SIMBLK;
        if (unext < NUNITS) {
            stage(cur ^ 1, unext);                       // prefetch next unit
            asm volatile("s_waitcnt vmcnt(16)" ::: "memory");  // only u's loads
        } else {
            asm volatile("s_waitcnt vmcnt(0)" ::: "memory");
        }
        __builtin_amdgcn_s_barrier();                    // buf[cur] ready on all waves
        __builtin_amdgcn_sched_barrier(0);

        int b, rt, ct; decode(ucur, b, rt, ct);

        f32x4 zero = {0.f, 0.f, 0.f, 0.f};
        f32x4 acc[4][4];
        #pragma unroll
        for (int m=0;m<4;++m)
            #pragma unroll
            for (int n=0;n<4;++n) acc[m][n] = zero;

        const unsigned char* Ab = &sA[cur][0];
        const unsigned char* Bb = &sB[cur][0];

        #pragma unroll
        for (int ks = 0; ks < 4; ++ks) {     // 512 / 128, no barriers
            const int kbase = (ks*4 + klane) * 2048;   // granule G = ks*4 + klane
            i32x8 af[4], bf[4];
            #pragma unroll
            for (int m=0;m<4;++m) {
                i32x4 lo = *reinterpret_cast<const i32x4*>(Ab + kbase + (wm*64 + m*16 + roff)*16);
                af[m] = __builtin_shufflevector(lo, z4, 0,1,2,3,4,5,6,7);
            }
            #pragma unroll
            for (int n=0;n<4;++n) {
                i32x4 lo = *reinterpret_cast<const i32x4*>(Bb + kbase + (wn*64 + n*16 + roff)*16);
                bf[n] = __builtin_shufflevector(lo, z4, 0,1,2,3,4,5,6,7);
            }
            #pragma unroll
            for (int m=0;m<4;++m)
                #pragma unroll
                for (int n=0;n<4;++n)
                    acc[m][n] = __builtin_amdgcn_mfma_scale_f32_16x16x128_f8f6f4(
                        af[m], bf[n], acc[m][n], 4, 4,   // cbsz=4 (FP4), blgp=4 (FP4)
                        0, SCALE_E8M0, 0, SCALE_E8M0);
        }

        // ---- fused epilogue ----
        // C/D layout (m89/m91, shape-determined per m128): col=lane&15, row=(lane>>4)*4+reg
        const int gr_base = rt*128 + wm*64;
        const int gc_base = ct*128 + wn*64;
        float rmax[4][4];
        float cmax[4];
        #pragma unroll
        for (int n=0;n<4;++n) cmax[n] = -2.0f;
        #pragma unroll
        for (int m=0;m<4;++m) {
            #pragma unroll
            for (int r=0;r<4;++r) {
                const int grow = gr_base + m*16 + ((lane>>4)<<2) + r;
                float mx = -2.0f;
                #pragma unroll
                for (int n=0;n<4;++n) {
                    const int gcol = gc_base + n*16 + (lane & 15);
                    float v = acc[m][n][r];
                    cmax[n] = fmaxf(cmax[n], v);
                    float vm = (grow == gcol) ? -2.0f : v;
                    mx = fmaxf(mx, vm);
                }
                rmax[m][r] = mx;
            }
        }
        #pragma unroll
        for (int s = 1; s < 16; s <<= 1) {
            #pragma unroll
            for (int m=0;m<4;++m)
                #pragma unroll
                for (int r=0;r<4;++r)
                    rmax[m][r] = fmaxf(rmax[m][r], __shfl_xor(rmax[m][r], s, 64));
        }
        if ((lane & 15) == 0) {
            #pragma unroll
            for (int m=0;m<4;++m)
                #pragma unroll
                for (int r=0;r<4;++r)
                    prow[wn][wm*64 + m*16 + ((lane>>4)<<2) + r] = rmax[m][r];
        }
        #pragma unroll
        for (int s = 16; s < 64; s <<= 1) {
            #pragma unroll
            for (int n=0;n<4;++n)
                cmax[n] = fmaxf(cmax[n], __shfl_xor(cmax[n], s, 64));
        }
        if (lane < 16) {
            #pragma unroll
            for (int n=0;n<4;++n)
                pcol[wm][wn*64 + n*16 + lane] = cmax[n];
        }
        // post-reduce fence WITHOUT vmcnt drain: prefetch stays in flight
        asm volatile("s_waitcnt lgkmcnt(0)" ::: "memory");  // prow/pcol visible
        __builtin_amdgcn_s_barrier();
        __builtin_amdgcn_sched_barrier(0);
        if (tid < 128) {
            float rv = fmaxf(prow[0][tid], prow[1][tid]);
            part[((size_t)b*NT + ct)*TDIM + (size_t)rt*128 + tid] = rv;
            if (rt != ct) {
                float cv = fmaxf(pcol[0][tid], pcol[1][tid]);
                part[((size_t)b*NT + rt)*TDIM + (size_t)ct*128 + tid] = cv;
            }
        }
        // next iteration's stage targets buf[cur] (all reads fenced above) and
        // its stage-ready barrier orders prow/pcol rewrite after these reads.
    }
}

// ---------------- kernel 3: gate * cached gelu ----------------
// slots aliases d_out: row r's slot bytes [0,256)=xq (dead), [512,1536)=gelu
// bf16. Each wave reads its own row's gelu then overwrites its own slot with
// the fp32 out row — load-before-store within the wave, race-free.
// XCD-aligned mapping: batch = blockIdx % 8.
__global__ __launch_bounds__(256) void finalize_kernel(
    char* slots,
    const float* __restrict__ part, const float* __restrict__ cosema,
    const float* __restrict__ p_log_tau, const float* __restrict__ p_log_sigma,
    const float* __restrict__ p_log_w)
{
    const int wave = threadIdx.x >> 6;
    const int lane = threadIdx.x & 63;
    const int b    = blockIdx.x & 7;          // batch == XCD
    const int ib   = blockIdx.x >> 3;         // 0..511 within batch
    const int row  = (b << 11) + ib * 4 + wave;
    const int t = row & 2047;

    const float tau   = __expf(p_log_tau[0]);
    const float sigma = log1pf(__expf(p_log_sigma[0])); // softplus
    const float wgt   = log1pf(__expf(p_log_w[0]));

    float nn = -2.0f;
    #pragma unroll
    for (int ctile = 0; ctile < NT; ++ctile)
        nn = fmaxf(nn, part[((size_t)b*NT + ctile)*TDIM + t]);
    nn = fminf(fmaxf(nn, -1.0f), 1.0f);

    const float novelty  = (1.0f - nn) * 0.5f;
    const float surprise = tanh_fast(sigma * novelty);
    const float gate = __expf(-tau * cosema[row]) * (1.0f + wgt * surprise);

    char* rowb = slots + (size_t)row * SLOTB;
    u16x8 hg = *reinterpret_cast<const u16x8*>(rowb + 512 + lane * 16);
    float4 o0, o1;
    o0.x = bf2f(hg[0]) * gate; o0.y = bf2f(hg[1]) * gate;
    o0.z = bf2f(hg[2]) * gate; o0.w = bf2f(hg[3]) * gate;
    o1.x = bf2f(hg[4]) * gate; o1.y = bf2f(hg[5]) * gate;
    o1.z = bf2f(hg[6]) * gate; o1.w = bf2f(hg[7]) * gate;
    float* orow = reinterpret_cast<float*>(rowb) + lane * 8;
    *reinterpret_cast<float4*>(orow)     = o0;
    *reinterpret_cast<float4*>(orow + 4) = o1;
}

extern "C" void kernel_launch(void* const* d_in, const int* in_sizes, int n_in,
                              void* d_out, int out_size, void* d_ws, size_t ws_size,
                              hipStream_t stream) {
    const float* x           = (const float*)d_in[0];
    // d_in[1] = logit_decay (unused by reference)
    const float* p_log_tau   = (const float*)d_in[2];
    const float* p_log_sigma = (const float*)d_in[3];
    const float* p_log_w     = (const float*)d_in[4];
    const float* ema         = (const float*)d_in[5];

    // d_out doubles as scratch: per-row 2048-B slots hold [fp4 xq | bf16 gelu]
    // until finalize overwrites each slot with the fp32 output row.
    char*  slots  = (char*)d_out;                      // B*T*SLOTB = 33.6 MB
    float* part   = (float*)d_ws;                      // B*NT*T*4 = 2 MB
    float* cosema = (float*)((char*)d_ws + (size_t)BATCH*NT*TDIM*sizeof(float));

    prep_kernel<<<dim3(BATCH*TDIM/4), 256, 0, stream>>>(x, ema, slots, cosema);
    simmax_kernel<<<dim3(SIMBLK), 256, 0, stream>>>(slots, part);
    finalize_kernel<<<dim3(BATCH*TDIM/4), 256, 0, stream>>>(
        slots, part, cosema, p_log_tau, p_log_sigma, p_log_w);
}

// Round 19
// 49.139 us; speedup vs baseline: 1.1753x; 1.1753x over previous
//
#include <hip/hip_runtime.h>
#include <math.h>

#define BATCH 8
#define TDIM 2048
#define DDIM 512
#define SLOTB 2048       // bytes per packed row slot: [256B fp4 xq | pad | 1024B gelu bf16 @512]
#define NT 16            // number of 128-row tiles per batch
#define NTRI (NT*(NT+1)/2)
#define SCALE_E8M0 122   // 2^-5 per operand: compensates the x32 pre-scale (2^-10 total)

typedef unsigned short u16;
typedef float f32x4 __attribute__((ext_vector_type(4)));
typedef u16 u16x8 __attribute__((ext_vector_type(8)));
typedef int i32x4 __attribute__((ext_vector_type(4)));
typedef int i32x8 __attribute__((ext_vector_type(8)));

// fast tanh via single v_exp_f32: tanh(u) = 1 - 2/(exp(2u)+1)
__device__ __forceinline__ float tanh_fast(float u) {
    float e = __expf(2.0f * u);
    return 1.0f - 2.0f / (e + 1.0f);
}

__device__ __forceinline__ float gelu_f(float x) {
    const float c = 0.7978845608028654f; // sqrt(2/pi)
    return 0.5f * x * (1.0f + tanh_fast(c * (x + 0.044715f * x * x * x)));
}

__device__ __forceinline__ u16 f2bf(float f) {
    unsigned u = __float_as_uint(f);
    return (u16)((u + 0x7FFFu + ((u >> 16) & 1u)) >> 16); // RNE, no NaN inputs
}
__device__ __forceinline__ float bf2f(u16 h) {
    return __uint_as_float(((unsigned)h) << 16);
}

__device__ __forceinline__ float wave_sum(float v) {
    #pragma unroll
    for (int s = 1; s < 64; s <<= 1) v += __shfl_xor(v, s, 64);
    return v;
}

__device__ __forceinline__ void load_lds16(const void* g, void* l) {
    __builtin_amdgcn_global_load_lds(
        (const __attribute__((address_space(1))) void*)g,
        (__attribute__((address_space(3))) void*)l, 16, 0, 0);
}

// ---------------- kernel 1: norms, cos_ema, fp4 xq (x_n*32) + bf16 gelu ----------------
// XCD-aligned mapping: batch = blockIdx % 8 (same pinning as simmax).
// fp4 e2m1 magnitudes {0,.5,1,1.5,2,3,4,6}: code = #thresholds passed (RNE bins),
// sign in bit 3. Nibble j of the lane's u32 = K-elem lane*8+j. Any consistent
// K-permutation of BOTH operands leaves the dot product invariant, so packing
// order cannot silently corrupt results.
__global__ __launch_bounds__(256) void prep_kernel(
    const float* __restrict__ x, const float* __restrict__ ema,
    char* __restrict__ slots, float* __restrict__ cosema)
{
    const int wave = threadIdx.x >> 6;
    const int lane = threadIdx.x & 63;
    const int xb   = blockIdx.x & 7;          // batch == XCD
    const int ib   = blockIdx.x >> 3;         // 0..511 within batch
    const int row  = (xb << 11) + ib * 4 + wave; // 0 .. B*T-1

    const float* xr = x + (size_t)row * DDIM + lane * 8;
    float4 v0 = *reinterpret_cast<const float4*>(xr);
    float4 v1 = *reinterpret_cast<const float4*>(xr + 4);
    const float* er = ema + lane * 8;
    float4 e0 = *reinterpret_cast<const float4*>(er);
    float4 e1 = *reinterpret_cast<const float4*>(er + 4);

    float vx[8] = {v0.x,v0.y,v0.z,v0.w,v1.x,v1.y,v1.z,v1.w};
    float ve[8] = {e0.x,e0.y,e0.z,e0.w,e1.x,e1.y,e1.z,e1.w};
    float gg[8];

    float ssx=0.f, ssg=0.f, dge=0.f, sse=0.f;
    #pragma unroll
    for (int j=0;j<8;++j) {
        float xv = vx[j];
        ssx += xv*xv;
        float gv = gelu_f(xv);
        gg[j] = gv;
        ssg += gv*gv;
        dge += gv*ve[j];
        sse += ve[j]*ve[j];
    }
    ssx = wave_sum(ssx); ssg = wave_sum(ssg);
    dge = wave_sum(dge); sse = wave_sum(sse);

    // quantize x_n * 32 to fp4 e2m1 (MFMA scales 2^-5 x 2^-5 restore the product)
    float invx32 = 32.0f / fmaxf(sqrtf(ssx), 1e-12f);
    unsigned pack = 0;
    #pragma unroll
    for (int j=0;j<8;++j) {
        float z = vx[j] * invx32;
        float a = fabsf(z);
        int c = (a>=0.25f) + (a>=0.75f) + (a>=1.25f) + (a>=1.75f)
              + (a>=2.5f)  + (a>=3.5f)  + (a>=5.0f);
        c |= (z < 0.0f) ? 8 : 0;
        pack |= (unsigned)c << (4*j);
    }
    char* rowb = slots + (size_t)row * SLOTB;
    reinterpret_cast<unsigned*>(rowb)[lane] = pack;   // fp4 bytes [0,256)

    u16x8 hg;
    #pragma unroll
    for (int j=0;j<8;++j) hg[j] = f2bf(gg[j]);
    *reinterpret_cast<u16x8*>(rowb + 512 + lane * 16) = hg;  // gelu bytes [512,1536)

    if (lane == 0) {
        float c = dge / (fmaxf(sqrtf(ssg), 1e-12f) * fmaxf(sqrtf(sse), 1e-12f));
        c = fminf(fmaxf(c, -1.0f), 1.0f);
        cosema[row] = c;
    }
}

// -------- kernel 2: Xn*Xn^T row-max via MX-fp4 K=128 — FULL-K in LDS, ONE barrier --------
// Best measured configuration (round 15, 48.8 us). One operand's full-K tile:
// 256B/row x 128 rows = 32 KB = 2048 granule-slots = 8 slots/thread. Stage
// everything, ONE __syncthreads, then all 64 MFMAs back-to-back — zero inner
// barriers. 66 KB LDS -> 2 blocks/CU: co-resident block computes while this
// one drains. Granule-major layout [G=16][row=128][16B]: 16-lane groups read
// 256 B contiguous -> conflict-free, no swizzle; global_load_lds linear dest
// maps directly (slot s = G*128+r at byte s*16; thread slot s = i*256+w*64+lane).
// T1 batch-per-XCD kept; diag tiles (rt==ct) alias B to A and skip B staging.
__global__ __launch_bounds__(256) void simmax_kernel(
    const char* __restrict__ slots, float* __restrict__ part)
{
    __shared__ unsigned char sA[32768];   // [G(16)][row(128)][16B]
    __shared__ unsigned char sB[32768];
    __shared__ float prow[2][128];
    __shared__ float pcol[2][128];

    const int tid  = threadIdx.x;
    const int lane = tid & 63;
    const int w    = tid >> 6;
    const int wm   = w >> 1, wn = w & 1;

    const int b = blockIdx.x & 7;        // batch == XCD (round-robin dispatch)
    // decode upper-triangular linear index -> (rt, ct), rt <= ct
    int rem = blockIdx.x >> 3, rt = 0;
    while (rem >= (NT - rt)) { rem -= (NT - rt); ++rt; }
    const int ct = rt + rem;
    const bool diag = (rt == ct);

    const char* Ag = slots + ((size_t)b * TDIM + (size_t)rt * 128) * SLOTB;
    const char* Bg = slots + ((size_t)b * TDIM + (size_t)ct * 128) * SLOTB;

    // ---- stage ALL K at once: 2048 slots per operand, 8 per thread ----
    #pragma unroll
    for (int i = 0; i < 8; ++i) {
        const int s = i*256 + tid;                   // 0..2047
        const int G = s >> 7, r = s & 127;           // granule 0..15, row 0..127
        const size_t srcoff = (size_t)r * SLOTB + G*16;
        load_lds16(Ag + srcoff, &sA[i*4096 + w*1024]);
        if (!diag)
            load_lds16(Bg + srcoff, &sB[i*4096 + w*1024]);
    }
    __syncthreads();                     // single drain: whole tile-pair resident

    f32x4 zero = {0.f, 0.f, 0.f, 0.f};
    f32x4 acc[4][4];
    #pragma unroll
    for (int m=0;m<4;++m)
        #pragma unroll
        for (int n=0;n<4;++n) acc[m][n] = zero;

    const int roff  = lane & 15;
    const int klane = lane >> 4;
    const unsigned char* Ab = &sA[0];
    const unsigned char* Bb = diag ? Ab : &sB[0];

    const i32x4 z4 = {0,0,0,0};
    #pragma unroll
    for (int ks = 0; ks < 4; ++ks) {     // 512 / 128, no barriers
        const int kbase = (ks*4 + klane) * 2048;   // granule G = ks*4 + klane
        i32x8 af[4], bf[4];
        #pragma unroll
        for (int m=0;m<4;++m) {
            i32x4 lo = *reinterpret_cast<const i32x4*>(Ab + kbase + (wm*64 + m*16 + roff)*16);
            af[m] = __builtin_shufflevector(lo, z4, 0,1,2,3,4,5,6,7);
        }
        #pragma unroll
        for (int n=0;n<4;++n) {
            i32x4 lo = *reinterpret_cast<const i32x4*>(Bb + kbase + (wn*64 + n*16 + roff)*16);
            bf[n] = __builtin_shufflevector(lo, z4, 0,1,2,3,4,5,6,7);
        }
        #pragma unroll
        for (int m=0;m<4;++m)
            #pragma unroll
            for (int n=0;n<4;++n)
                acc[m][n] = __builtin_amdgcn_mfma_scale_f32_16x16x128_f8f6f4(
                    af[m], bf[n], acc[m][n], 4, 4,   // cbsz=4 (FP4), blgp=4 (FP4)
                    0, SCALE_E8M0, 0, SCALE_E8M0);
    }

    // ---- fused epilogue ----
    // C/D layout (m89/m91, shape-determined per m128): col = lane&15, row = (lane>>4)*4 + reg
    const int gr_base = rt*128 + wm*64;
    const int gc_base = ct*128 + wn*64;
    float rmax[4][4]; // [m][reg]  row-max (diag-masked)
    float cmax[4];    // [n]       col-max (unmasked; used when rt<ct)
    #pragma unroll
    for (int n=0;n<4;++n) cmax[n] = -2.0f;
    #pragma unroll
    for (int m=0;m<4;++m) {
        #pragma unroll
        for (int r=0;r<4;++r) {
            const int grow = gr_base + m*16 + ((lane>>4)<<2) + r;
            float mx = -2.0f;
            #pragma unroll
            for (int n=0;n<4;++n) {
                const int gcol = gc_base + n*16 + (lane & 15);
                float v = acc[m][n][r];
                cmax[n] = fmaxf(cmax[n], v);
                float vm = (grow == gcol) ? -2.0f : v;
                mx = fmaxf(mx, vm);
            }
            rmax[m][r] = mx;
        }
    }
    // row-max: butterfly across the 16-lane column group
    #pragma unroll
    for (int s = 1; s < 16; s <<= 1) {
        #pragma unroll
        for (int m=0;m<4;++m)
            #pragma unroll
            for (int r=0;r<4;++r)
                rmax[m][r] = fmaxf(rmax[m][r], __shfl_xor(rmax[m][r], s, 64));
    }
    if ((lane & 15) == 0) {
        #pragma unroll
        for (int m=0;m<4;++m)
            #pragma unroll
            for (int r=0;r<4;++r)
                prow[wn][wm*64 + m*16 + ((lane>>4)<<2) + r] = rmax[m][r];
    }
    // col-max: butterfly across the 4 row-groups
    #pragma unroll
    for (int s = 16; s < 64; s <<= 1) {
        #pragma unroll
        for (int n=0;n<4;++n)
            cmax[n] = fmaxf(cmax[n], __shfl_xor(cmax[n], s, 64));
    }
    if (lane < 16) {
        #pragma unroll
        for (int n=0;n<4;++n)
            pcol[wm][wn*64 + n*16 + lane] = cmax[n];
    }
    __syncthreads();
    if (tid < 128) {
        float rv = fmaxf(prow[0][tid], prow[1][tid]);
        part[((size_t)b*NT + ct)*TDIM + (size_t)rt*128 + tid] = rv;
        if (rt != ct) {
            float cv = fmaxf(pcol[0][tid], pcol[1][tid]);
            part[((size_t)b*NT + rt)*TDIM + (size_t)ct*128 + tid] = cv;
        }
    }
}

// ---------------- kernel 3: gate * cached gelu ----------------
// slots aliases d_out: row r's slot bytes [0,256)=xq (dead), [512,1536)=gelu
// bf16. Each wave reads its own row's gelu then overwrites its own slot with
// the fp32 out row — load-before-store within the wave, race-free.
// XCD-aligned mapping: batch = blockIdx % 8.
__global__ __launch_bounds__(256) void finalize_kernel(
    char* slots,
    const float* __restrict__ part, const float* __restrict__ cosema,
    const float* __restrict__ p_log_tau, const float* __restrict__ p_log_sigma,
    const float* __restrict__ p_log_w)
{
    const int wave = threadIdx.x >> 6;
    const int lane = threadIdx.x & 63;
    const int b    = blockIdx.x & 7;          // batch == XCD
    const int ib   = blockIdx.x >> 3;         // 0..511 within batch
    const int row  = (b << 11) + ib * 4 + wave;
    const int t = row & 2047;

    const float tau   = __expf(p_log_tau[0]);
    const float sigma = log1pf(__expf(p_log_sigma[0])); // softplus
    const float wgt   = log1pf(__expf(p_log_w[0]));

    float nn = -2.0f;
    #pragma unroll
    for (int ctile = 0; ctile < NT; ++ctile)
        nn = fmaxf(nn, part[((size_t)b*NT + ctile)*TDIM + t]);
    nn = fminf(fmaxf(nn, -1.0f), 1.0f);

    const float novelty  = (1.0f - nn) * 0.5f;
    const float surprise = tanh_fast(sigma * novelty);
    const float gate = __expf(-tau * cosema[row]) * (1.0f + wgt * surprise);

    char* rowb = slots + (size_t)row * SLOTB;
    u16x8 hg = *reinterpret_cast<const u16x8*>(rowb + 512 + lane * 16);
    float4 o0, o1;
    o0.x = bf2f(hg[0]) * gate; o0.y = bf2f(hg[1]) * gate;
    o0.z = bf2f(hg[2]) * gate; o0.w = bf2f(hg[3]) * gate;
    o1.x = bf2f(hg[4]) * gate; o1.y = bf2f(hg[5]) * gate;
    o1.z = bf2f(hg[6]) * gate; o1.w = bf2f(hg[7]) * gate;
    float* orow = reinterpret_cast<float*>(rowb) + lane * 8;
    *reinterpret_cast<float4*>(orow)     = o0;
    *reinterpret_cast<float4*>(orow + 4) = o1;
}

extern "C" void kernel_launch(void* const* d_in, const int* in_sizes, int n_in,
                              void* d_out, int out_size, void* d_ws, size_t ws_size,
                              hipStream_t stream) {
    const float* x           = (const float*)d_in[0];
    // d_in[1] = logit_decay (unused by reference)
    const float* p_log_tau   = (const float*)d_in[2];
    const float* p_log_sigma = (const float*)d_in[3];
    const float* p_log_w     = (const float*)d_in[4];
    const float* ema         = (const float*)d_in[5];

    // d_out doubles as scratch: per-row 2048-B slots hold [fp4 xq | bf16 gelu]
    // until finalize overwrites each slot with the fp32 output row.
    char*  slots  = (char*)d_out;                      // B*T*SLOTB = 33.6 MB
    float* part   = (float*)d_ws;                      // B*NT*T*4 = 2 MB
    float* cosema = (float*)((char*)d_ws + (size_t)BATCH*NT*TDIM*sizeof(float));

    prep_kernel<<<dim3(BATCH*TDIM/4), 256, 0, stream>>>(x, ema, slots, cosema);
    simmax_kernel<<<dim3(NTRI*BATCH), 256, 0, stream>>>(slots, part);
    finalize_kernel<<<dim3(BATCH*TDIM/4), 256, 0, stream>>>(
        slots, part, cosema, p_log_tau, p_log_sigma, p_log_w);
}